// Round 10
// baseline (914.329 us; speedup 1.0000x reference)
//
#include <hip/hip_runtime.h>

#define NN 50000
#define NE 800000
#define FF 128
#define KF 8
#define DD 16
#define GG 512
#define BN_EPS 1e-5f
#define NB 196   // ceil(NN/256)
#define KSTR 264 // padded k-block stride for block-diag weights

// ---------------- CSR build ----------------
__global__ void k_deg(const int* __restrict__ dst, int* __restrict__ deg) {
    int e = blockIdx.x * 256 + threadIdx.x;
    if (e < NE) atomicAdd(&deg[dst[e]], 1);
}

__global__ __launch_bounds__(256) void k_bsum(const int* __restrict__ deg, int* __restrict__ bsum) {
    int idx = blockIdx.x * 256 + threadIdx.x;
    int v = (idx < NN) ? deg[idx] : 0;
#pragma unroll
    for (int off = 32; off; off >>= 1) v += __shfl_down(v, off, 64);
    __shared__ int ws[4];
    if ((threadIdx.x & 63) == 0) ws[threadIdx.x >> 6] = v;
    __syncthreads();
    if (threadIdx.x == 0) bsum[blockIdx.x] = ws[0] + ws[1] + ws[2] + ws[3];
}

__global__ __launch_bounds__(256) void k_bscan(const int* __restrict__ bsum, int* __restrict__ boffs) {
    __shared__ int s[256];
    int tid = threadIdx.x;
    int v = (tid < NB) ? bsum[tid] : 0;
    s[tid] = v;
    __syncthreads();
    for (int off = 1; off < 256; off <<= 1) {
        int t = (tid >= off) ? s[tid - off] : 0;
        __syncthreads();
        s[tid] += t;
        __syncthreads();
    }
    if (tid < NB) boffs[tid] = s[tid] - v;  // exclusive
}

__global__ __launch_bounds__(256) void k_offs(const int* __restrict__ deg,
                                              const int* __restrict__ boffs,
                                              int* __restrict__ offs) {
    __shared__ int s[256];
    int tid = threadIdx.x;
    int idx = blockIdx.x * 256 + tid;
    int v = (idx < NN) ? deg[idx] : 0;
    s[tid] = v;
    __syncthreads();
    for (int off = 1; off < 256; off <<= 1) {
        int t = (tid >= off) ? s[tid - off] : 0;
        __syncthreads();
        s[tid] += t;
        __syncthreads();
    }
    int incl = s[tid];
    if (idx < NN) offs[idx] = boffs[blockIdx.x] + incl - v;
    if (idx == NN - 1) offs[NN] = boffs[blockIdx.x] + incl;
}

__global__ void k_fill(const int* __restrict__ src, const int* __restrict__ dst,
                       const int* __restrict__ offs, int* __restrict__ cnt,
                       int* __restrict__ csr) {
    int e = blockIdx.x * 256 + threadIdx.x;
    if (e < NE) {
        int d = dst[e];
        int p = atomicAdd(&cnt[d], 1);
        csr[offs[d] + p] = src[e];
    }
}

// ---------------- shared device helpers ----------------
__device__ __forceinline__ void bn_coefs(const float* st, const float* g, const float* be,
                                         int lane, float4& a4, float4& b4) {
    const float inv_n = 1.0f / (float)NN;
    float av[4], bv[4];
#pragma unroll
    for (int t = 0; t < 4; t++) {
        int c = lane * 4 + t;
        float mu = st[c] * inv_n;
        float var = st[FF + c] * inv_n - mu * mu;
        float a = g[c] * rsqrtf(var + BN_EPS);
        av[t] = a;
        bv[t] = be[c] - mu * a;
    }
    a4 = make_float4(av[0], av[1], av[2], av[3]);
    b4 = make_float4(bv[0], bv[1], bv[2], bv[3]);
}

// gather macro body: accumulates f(X[row]) + sum f(X[nb]) for one float4 column c4,
// f = optional BN affine (+relu). Writes result f-major into Af. BN coefs come from
// cA/cB (LDS). Used inside fused kernels (inlined to keep LDS addressing).
#define GATHER_BODY(BN_, RELU_)                                                      \
    {                                                                                \
        int r = tid >> 2, q = tid & 3;                                               \
        int gr = row0 + r;                                                           \
        if (gr >= NN) gr = NN - 1;                                                   \
        int e0 = offs[gr], e1 = offs[gr + 1];                                        \
        const float4* Xr = X + (size_t)gr * 32;                                      \
        _Pragma("unroll")                                                            \
        for (int j = 0; j < 8; j++) {                                                \
            int c4 = q + 4 * j;                                                      \
            float4 a4 = make_float4(1.f, 1.f, 1.f, 1.f);                             \
            float4 b4 = make_float4(0.f, 0.f, 0.f, 0.f);                             \
            if (BN_) {                                                               \
                a4 = *(const float4*)&cA[c4 * 4];                                    \
                b4 = *(const float4*)&cB[c4 * 4];                                    \
            }                                                                        \
            auto apply = [&](float4 v) -> float4 {                                   \
                if (BN_) {                                                           \
                    v.x = fmaf(v.x, a4.x, b4.x);                                     \
                    v.y = fmaf(v.y, a4.y, b4.y);                                     \
                    v.z = fmaf(v.z, a4.z, b4.z);                                     \
                    v.w = fmaf(v.w, a4.w, b4.w);                                     \
                }                                                                    \
                if (RELU_) {                                                         \
                    v.x = fmaxf(v.x, 0.f);                                           \
                    v.y = fmaxf(v.y, 0.f);                                           \
                    v.z = fmaxf(v.z, 0.f);                                           \
                    v.w = fmaxf(v.w, 0.f);                                           \
                }                                                                    \
                return v;                                                            \
            };                                                                       \
            auto add4 = [](float4& a, float4 b) {                                    \
                a.x += b.x; a.y += b.y; a.z += b.z; a.w += b.w;                       \
            };                                                                       \
            float4 acc = apply(Xr[c4]);                                              \
            int e = e0;                                                              \
            for (; e + 8 <= e1; e += 8) {                                            \
                int s0 = csr[e], s1 = csr[e + 1], s2 = csr[e + 2], s3 = csr[e + 3];  \
                int s4 = csr[e + 4], s5 = csr[e + 5], s6 = csr[e + 6], s7 = csr[e + 7];\
                float4 v0 = X[(size_t)s0 * 32 + c4];                                 \
                float4 v1 = X[(size_t)s1 * 32 + c4];                                 \
                float4 v2 = X[(size_t)s2 * 32 + c4];                                 \
                float4 v3 = X[(size_t)s3 * 32 + c4];                                 \
                float4 v4 = X[(size_t)s4 * 32 + c4];                                 \
                float4 v5 = X[(size_t)s5 * 32 + c4];                                 \
                float4 v6 = X[(size_t)s6 * 32 + c4];                                 \
                float4 v7 = X[(size_t)s7 * 32 + c4];                                 \
                v0 = apply(v0); v1 = apply(v1); v2 = apply(v2); v3 = apply(v3);      \
                v4 = apply(v4); v5 = apply(v5); v6 = apply(v6); v7 = apply(v7);      \
                add4(v0, v1); add4(v2, v3); add4(v4, v5); add4(v6, v7);              \
                add4(v0, v2); add4(v4, v6); add4(v0, v4); add4(acc, v0);             \
            }                                                                        \
            for (; e + 4 <= e1; e += 4) {                                            \
                int s0 = csr[e], s1 = csr[e + 1], s2 = csr[e + 2], s3 = csr[e + 3];  \
                float4 v0 = apply(X[(size_t)s0 * 32 + c4]);                          \
                float4 v1 = apply(X[(size_t)s1 * 32 + c4]);                          \
                float4 v2 = apply(X[(size_t)s2 * 32 + c4]);                          \
                float4 v3 = apply(X[(size_t)s3 * 32 + c4]);                          \
                add4(v0, v1); add4(v2, v3); add4(v0, v2); add4(acc, v0);             \
            }                                                                        \
            for (; e < e1; e++) {                                                    \
                float4 v = apply(X[(size_t)csr[e] * 32 + c4]);                       \
                add4(acc, v);                                                        \
            }                                                                        \
            int fb = c4 * 4;                                                         \
            Af[(fb + 0) * 68 + r] = acc.x;                                           \
            Af[(fb + 1) * 68 + r] = acc.y;                                           \
            Af[(fb + 2) * 68 + r] = acc.z;                                           \
            Af[(fb + 3) * 68 + r] = acc.w;                                           \
        }                                                                            \
    }

// ============ fused agg + GEMM pair: C = relu(agg(f(X))@W1+b1)@W2+b2, + stats ======
// 64-row tiles, 782 blocks. Gather (L3-latency-bound) and GEMM (VALU-bound) phases
// of different blocks co-schedule on a CU. A gathered once into Af (f-major, b128
// fragment reads); z overwrites Af; only W chunks restage per 32-f step.
// LDS = Af 34.8K + Ws 16K = 51.2K -> 3 blocks/CU. No register prefetch (spills).
template <bool BN, bool RELU>
__global__ __launch_bounds__(256, 2) void k_fuse_pair(
    const float4* __restrict__ X, const int* __restrict__ offs, const int* __restrict__ csr,
    const float* __restrict__ st, const float* __restrict__ g, const float* __restrict__ be,
    const float* __restrict__ W1, const float* __restrict__ b1,
    const float* __restrict__ W2, const float* __restrict__ b2,
    float* __restrict__ C, float* __restrict__ stout) {
    __shared__ float Af[128 * 68];  // f-major A tile, then f-major z tile
    __shared__ float Ws[32 * 128];  // W chunk; [0..255] = BN coefs during gather
    int tid = threadIdx.x;
    int row0 = blockIdx.x * 64;
    float* cA = Ws;
    float* cB = Ws + 128;

    if (BN) {
        if (tid < 128) {
            const float inv_n = 1.0f / (float)NN;
            float mu = st[tid] * inv_n;
            float var = st[FF + tid] * inv_n - mu * mu;
            float a = g[tid] * rsqrtf(var + BN_EPS);
            cA[tid] = a;
            cB[tid] = be[tid] - mu * a;
        }
        __syncthreads();
    }

    GATHER_BODY(BN, RELU)
    __syncthreads();  // Af complete; coef reads done (Ws may be overwritten now)

    int m = tid & 15;
    int tr = (tid >> 4) << 2;
    int c0 = m << 2, c1 = 64 + (m << 2);
    float acc[4][8];
#pragma unroll
    for (int i = 0; i < 4; i++)
#pragma unroll
        for (int j = 0; j < 8; j++) acc[i][j] = 0.f;

    // ---- phase 1: z = relu(A@W1 + b1) ----
    for (int c = 0; c < 4; c++) {
#pragma unroll
        for (int i = 0; i < 4; i++) {
            int l = tid + i * 256;
            int f = l >> 5, q = l & 31;
            ((float4*)Ws)[f * 32 + q] = ((const float4*)W1)[(size_t)(c * 32 + f) * 32 + q];
        }
        __syncthreads();
#pragma unroll 8
        for (int f = 0; f < 32; f++) {
            float4 a04 = *(const float4*)&Af[(c * 32 + f) * 68 + tr];
            float a[4] = {a04.x, a04.y, a04.z, a04.w};
            float4 w0 = *(const float4*)&Ws[f * 128 + c0];
            float4 w1 = *(const float4*)&Ws[f * 128 + c1];
            float w[8] = {w0.x, w0.y, w0.z, w0.w, w1.x, w1.y, w1.z, w1.w};
#pragma unroll
            for (int i = 0; i < 4; i++)
#pragma unroll
                for (int j = 0; j < 8; j++) acc[i][j] = fmaf(a[i], w[j], acc[i][j]);
        }
        __syncthreads();
    }

    // z = relu(acc+b1) -> Af, f-major (thread owns cols c0..c0+3, c1..c1+3)
    {
        float4 bb0 = *(const float4*)&b1[c0];
        float4 bb1 = *(const float4*)&b1[c1];
        float bb[8] = {bb0.x, bb0.y, bb0.z, bb0.w, bb1.x, bb1.y, bb1.z, bb1.w};
#pragma unroll
        for (int i = 0; i < 4; i++) {
#pragma unroll
            for (int t = 0; t < 4; t++) {
                Af[(c0 + t) * 68 + tr + i] = fmaxf(acc[i][t] + bb[t], 0.f);
                Af[(c1 + t) * 68 + tr + i] = fmaxf(acc[i][4 + t] + bb[4 + t], 0.f);
            }
        }
#pragma unroll
        for (int i = 0; i < 4; i++)
#pragma unroll
            for (int j = 0; j < 8; j++) acc[i][j] = 0.f;
    }

    // ---- phase 2: C = z@W2 + b2 ----
    for (int c = 0; c < 4; c++) {
#pragma unroll
        for (int i = 0; i < 4; i++) {
            int l = tid + i * 256;
            int f = l >> 5, q = l & 31;
            ((float4*)Ws)[f * 32 + q] = ((const float4*)W2)[(size_t)(c * 32 + f) * 32 + q];
        }
        __syncthreads();  // c=0: also covers z writes
#pragma unroll 8
        for (int f = 0; f < 32; f++) {
            float4 a04 = *(const float4*)&Af[(c * 32 + f) * 68 + tr];
            float a[4] = {a04.x, a04.y, a04.z, a04.w};
            float4 w0 = *(const float4*)&Ws[f * 128 + c0];
            float4 w1 = *(const float4*)&Ws[f * 128 + c1];
            float w[8] = {w0.x, w0.y, w0.z, w0.w, w1.x, w1.y, w1.z, w1.w};
#pragma unroll
            for (int i = 0; i < 4; i++)
#pragma unroll
                for (int j = 0; j < 8; j++) acc[i][j] = fmaf(a[i], w[j], acc[i][j]);
        }
        __syncthreads();
    }

    // ---- epilogue: bias, store, fused stats ----
    float cs[8], cq[8];
#pragma unroll
    for (int j = 0; j < 8; j++) { cs[j] = 0.f; cq[j] = 0.f; }
    {
        float4 bb0 = *(const float4*)&b2[c0];
        float4 bb1 = *(const float4*)&b2[c1];
        float bb[8] = {bb0.x, bb0.y, bb0.z, bb0.w, bb1.x, bb1.y, bb1.z, bb1.w};
#pragma unroll
        for (int i = 0; i < 4; i++) {
            int r = row0 + tr + i;
            if (r < NN) {
                float v[8];
#pragma unroll
                for (int j = 0; j < 8; j++) {
                    v[j] = acc[i][j] + bb[j];
                    cs[j] += v[j];
                    cq[j] += v[j] * v[j];
                }
                *(float4*)&C[(size_t)r * 128 + c0] = make_float4(v[0], v[1], v[2], v[3]);
                *(float4*)&C[(size_t)r * 128 + c1] = make_float4(v[4], v[5], v[6], v[7]);
            }
        }
    }
    {
        float* S1 = Ws;
        float* S2 = Ws + 2048;
        int grp = tid >> 4;
#pragma unroll
        for (int j = 0; j < 8; j++) {
            int c = (j < 4) ? c0 + j : c1 + (j - 4);
            S1[grp * 128 + c] = cs[j];
            S2[grp * 128 + c] = cq[j];
        }
        __syncthreads();
        if (tid < 128) {
            float s = 0.f, q = 0.f;
#pragma unroll
            for (int gi = 0; gi < 16; gi++) {
                s += S1[gi * 128 + tid];
                q += S2[gi * 128 + tid];
            }
            atomicAdd(&stout[tid], s);
            atomicAdd(&stout[FF + tid], q);
        }
    }
}

// ============ fused agg + h0: C = relu(agg(bn(X))@W1cat+b1) @ bd(W2) + b2, + stats ==
__global__ __launch_bounds__(256, 2) void k_fuse_h0(
    const float4* __restrict__ X, const int* __restrict__ offs, const int* __restrict__ csr,
    const float* __restrict__ st, const float* __restrict__ g, const float* __restrict__ be,
    const float* __restrict__ W1,  // [K,F,d]
    const float* __restrict__ b1,  // [K*d]
    const float* __restrict__ W2,  // [K,d,d]
    const float* __restrict__ b2,  // [K*d]
    float* __restrict__ C, float* __restrict__ stout) {
    __shared__ float Af[128 * 68];
    __shared__ float Ws[32 * 128];
    int tid = threadIdx.x;
    int row0 = blockIdx.x * 64;
    float* cA = Ws;
    float* cB = Ws + 128;

    if (tid < 128) {
        const float inv_n = 1.0f / (float)NN;
        float mu = st[tid] * inv_n;
        float var = st[FF + tid] * inv_n - mu * mu;
        float a = g[tid] * rsqrtf(var + BN_EPS);
        cA[tid] = a;
        cB[tid] = be[tid] - mu * a;
    }
    __syncthreads();

    GATHER_BODY(true, false)
    __syncthreads();

    int m = tid & 15;
    int tr = (tid >> 4) << 2;
    int c0 = m << 2, c1 = 64 + (m << 2);
    float acc[4][8];
#pragma unroll
    for (int i = 0; i < 4; i++)
#pragma unroll
        for (int j = 0; j < 8; j++) acc[i][j] = 0.f;

    // ---- phase 1: z = relu(A@W1cat + b1), W1 repacked on stage ----
    for (int c = 0; c < 4; c++) {
#pragma unroll
        for (int i = 0; i < 4; i++) {
            int l = tid + i * 256;
            int f = l >> 5, q = l & 31;
            float4 wv = *(const float4*)&W1[(q >> 2) * (FF * DD) + (size_t)(c * 32 + f) * DD + (q & 3) * 4];
            ((float4*)Ws)[f * 32 + q] = wv;
        }
        __syncthreads();
#pragma unroll 8
        for (int f = 0; f < 32; f++) {
            float4 a04 = *(const float4*)&Af[(c * 32 + f) * 68 + tr];
            float a[4] = {a04.x, a04.y, a04.z, a04.w};
            float4 w0 = *(const float4*)&Ws[f * 128 + c0];
            float4 w1 = *(const float4*)&Ws[f * 128 + c1];
            float w[8] = {w0.x, w0.y, w0.z, w0.w, w1.x, w1.y, w1.z, w1.w};
#pragma unroll
            for (int i = 0; i < 4; i++)
#pragma unroll
                for (int j = 0; j < 8; j++) acc[i][j] = fmaf(a[i], w[j], acc[i][j]);
        }
        __syncthreads();
    }

    // z -> Af f-major
    {
        float4 bb0 = *(const float4*)&b1[c0];
        float4 bb1 = *(const float4*)&b1[c1];
        float bb[8] = {bb0.x, bb0.y, bb0.z, bb0.w, bb1.x, bb1.y, bb1.z, bb1.w};
#pragma unroll
        for (int i = 0; i < 4; i++) {
#pragma unroll
            for (int t = 0; t < 4; t++) {
                Af[(c0 + t) * 68 + tr + i] = fmaxf(acc[i][t] + bb[t], 0.f);
                Af[(c1 + t) * 68 + tr + i] = fmaxf(acc[i][4 + t] + bb[4 + t], 0.f);
            }
        }
    }
    // stage W2 [K,16,16] at KSTR into Ws
    for (int l = tid; l < KF * 256; l += 256) {
        int k = l >> 8, r2 = l & 255;
        Ws[k * KSTR + r2] = W2[l];
    }
    __syncthreads();

    // block-diag product (z f-major in Af)
    int k0 = m >> 2, k1 = 4 + (m >> 2);
    int j0 = (m & 3) << 2;
    float y[4][8];
#pragma unroll
    for (int i = 0; i < 4; i++)
#pragma unroll
        for (int j = 0; j < 8; j++) y[i][j] = 0.f;
#pragma unroll
    for (int ii = 0; ii < 16; ii++) {
        float4 za0 = *(const float4*)&Af[(k0 * 16 + ii) * 68 + tr];
        float4 za1 = *(const float4*)&Af[(k1 * 16 + ii) * 68 + tr];
        float a0[4] = {za0.x, za0.y, za0.z, za0.w};
        float a1[4] = {za1.x, za1.y, za1.z, za1.w};
        float4 w0 = *(const float4*)&Ws[k0 * KSTR + ii * 16 + j0];
        float4 w1 = *(const float4*)&Ws[k1 * KSTR + ii * 16 + j0];
#pragma unroll
        for (int i = 0; i < 4; i++) {
            y[i][0] = fmaf(a0[i], w0.x, y[i][0]);
            y[i][1] = fmaf(a0[i], w0.y, y[i][1]);
            y[i][2] = fmaf(a0[i], w0.z, y[i][2]);
            y[i][3] = fmaf(a0[i], w0.w, y[i][3]);
            y[i][4] = fmaf(a1[i], w1.x, y[i][4]);
            y[i][5] = fmaf(a1[i], w1.y, y[i][5]);
            y[i][6] = fmaf(a1[i], w1.z, y[i][6]);
            y[i][7] = fmaf(a1[i], w1.w, y[i][7]);
        }
    }

    float cs[8], cq[8];
#pragma unroll
    for (int j = 0; j < 8; j++) { cs[j] = 0.f; cq[j] = 0.f; }
    {
        float4 bb0 = *(const float4*)&b2[c0];
        float4 bb1 = *(const float4*)&b2[c1];
        float bb[8] = {bb0.x, bb0.y, bb0.z, bb0.w, bb1.x, bb1.y, bb1.z, bb1.w};
#pragma unroll
        for (int i = 0; i < 4; i++) {
            int r = row0 + tr + i;
            if (r < NN) {
                float v[8];
#pragma unroll
                for (int j = 0; j < 8; j++) {
                    v[j] = y[i][j] + bb[j];
                    cs[j] += v[j];
                    cq[j] += v[j] * v[j];
                }
                *(float4*)&C[(size_t)r * 128 + c0] = make_float4(v[0], v[1], v[2], v[3]);
                *(float4*)&C[(size_t)r * 128 + c1] = make_float4(v[4], v[5], v[6], v[7]);
            }
        }
    }
    {
        float* S1 = Ws;
        float* S2 = Ws + 2048;
        int grp = tid >> 4;
        __syncthreads();  // block-diag W2 reads done
#pragma unroll
        for (int j = 0; j < 8; j++) {
            int c = (j < 4) ? c0 + j : c1 + (j - 4);
            S1[grp * 128 + c] = cs[j];
            S2[grp * 128 + c] = cq[j];
        }
        __syncthreads();
        if (tid < 128) {
            float s = 0.f, q = 0.f;
#pragma unroll
            for (int gi = 0; gi < 16; gi++) {
                s += S1[gi * 128 + tid];
                q += S2[gi * 128 + tid];
            }
            atomicAdd(&stout[tid], s);
            atomicAdd(&stout[FF + tid], q);
        }
    }
}

// ---------------- fused h1: agg(BN+relu on load) + double block-diag MLP -----------
__global__ __launch_bounds__(256) void k_aggbd(const float4* __restrict__ X,
                                               const int* __restrict__ offs,
                                               const int* __restrict__ csr,
                                               const float* __restrict__ st,
                                               const float* __restrict__ g,
                                               const float* __restrict__ be,
                                               const float* __restrict__ W1,
                                               const float4* __restrict__ b1,
                                               const float* __restrict__ W2,
                                               const float4* __restrict__ b2,
                                               float4* __restrict__ C) {
    __shared__ float As[8][128];
    __shared__ float Ts[8][128];
    __shared__ float Ws1[KF * KSTR];
    __shared__ float Ws2[KF * KSTR];
    int grp = threadIdx.x >> 5, lane = threadIdx.x & 31;
    int n = blockIdx.x * 8 + grp;

    for (int l = threadIdx.x; l < KF * 256; l += 256) {
        int k = l >> 8, r = l & 255;
        Ws1[k * KSTR + r] = W1[l];
        Ws2[k * KSTR + r] = W2[l];
    }

    float4 a4, b4;
    bn_coefs(st, g, be, lane, a4, b4);
    auto apply = [&](float4 v) -> float4 {
        v.x = fmaxf(fmaf(v.x, a4.x, b4.x), 0.f);
        v.y = fmaxf(fmaf(v.y, a4.y, b4.y), 0.f);
        v.z = fmaxf(fmaf(v.z, a4.z, b4.z), 0.f);
        v.w = fmaxf(fmaf(v.w, a4.w, b4.w), 0.f);
        return v;
    };
    auto add4 = [](float4& a, float4 b) {
        a.x += b.x; a.y += b.y; a.z += b.z; a.w += b.w;
    };

    float4 acc = apply(X[(size_t)n * 32 + lane]);
    int e0 = offs[n], e1 = offs[n + 1];
    int e = e0;
    for (; e + 8 <= e1; e += 8) {
        int s0 = csr[e], s1 = csr[e + 1], s2 = csr[e + 2], s3 = csr[e + 3];
        int s4 = csr[e + 4], s5 = csr[e + 5], s6 = csr[e + 6], s7 = csr[e + 7];
        float4 v0 = X[(size_t)s0 * 32 + lane];
        float4 v1 = X[(size_t)s1 * 32 + lane];
        float4 v2 = X[(size_t)s2 * 32 + lane];
        float4 v3 = X[(size_t)s3 * 32 + lane];
        float4 v4 = X[(size_t)s4 * 32 + lane];
        float4 v5 = X[(size_t)s5 * 32 + lane];
        float4 v6 = X[(size_t)s6 * 32 + lane];
        float4 v7 = X[(size_t)s7 * 32 + lane];
        v0 = apply(v0); v1 = apply(v1); v2 = apply(v2); v3 = apply(v3);
        v4 = apply(v4); v5 = apply(v5); v6 = apply(v6); v7 = apply(v7);
        add4(v0, v1); add4(v2, v3); add4(v4, v5); add4(v6, v7);
        add4(v0, v2); add4(v4, v6); add4(v0, v4); add4(acc, v0);
    }
    for (; e + 4 <= e1; e += 4) {
        int s0 = csr[e], s1 = csr[e + 1], s2 = csr[e + 2], s3 = csr[e + 3];
        float4 v0 = apply(X[(size_t)s0 * 32 + lane]);
        float4 v1 = apply(X[(size_t)s1 * 32 + lane]);
        float4 v2 = apply(X[(size_t)s2 * 32 + lane]);
        float4 v3 = apply(X[(size_t)s3 * 32 + lane]);
        add4(v0, v1); add4(v2, v3); add4(v0, v2); add4(acc, v0);
    }
    for (; e < e1; e++) {
        float4 v = apply(X[(size_t)csr[e] * 32 + lane]);
        add4(acc, v);
    }
    ((float4*)&As[grp][0])[lane] = acc;
    __syncthreads();

    int k = lane >> 2, jb = (lane & 3) * 4;
    float a[16];
    {
        const float4* As4 = (const float4*)&As[grp][k * 16];
        float4 a0 = As4[0], a1 = As4[1], a2 = As4[2], a3 = As4[3];
        a[0] = a0.x; a[1] = a0.y; a[2] = a0.z; a[3] = a0.w;
        a[4] = a1.x; a[5] = a1.y; a[6] = a1.z; a[7] = a1.w;
        a[8] = a2.x; a[9] = a2.y; a[10] = a2.z; a[11] = a2.w;
        a[12] = a3.x; a[13] = a3.y; a[14] = a3.z; a[15] = a3.w;
    }
    const float* wp1 = &Ws1[k * KSTR + jb];
    float4 t = b1[lane];
#pragma unroll
    for (int i = 0; i < 16; i++) {
        float4 wv = *(const float4*)&wp1[i * 16];
        t.x = fmaf(a[i], wv.x, t.x);
        t.y = fmaf(a[i], wv.y, t.y);
        t.z = fmaf(a[i], wv.z, t.z);
        t.w = fmaf(a[i], wv.w, t.w);
    }
    t.x = fmaxf(t.x, 0.f); t.y = fmaxf(t.y, 0.f);
    t.z = fmaxf(t.z, 0.f); t.w = fmaxf(t.w, 0.f);
    ((float4*)&Ts[grp][0])[lane] = t;
    __syncthreads();

    float b[16];
    {
        const float4* Ts4 = (const float4*)&Ts[grp][k * 16];
        float4 a0 = Ts4[0], a1 = Ts4[1], a2 = Ts4[2], a3 = Ts4[3];
        b[0] = a0.x; b[1] = a0.y; b[2] = a0.z; b[3] = a0.w;
        b[4] = a1.x; b[5] = a1.y; b[6] = a1.z; b[7] = a1.w;
        b[8] = a2.x; b[9] = a2.y; b[10] = a2.z; b[11] = a2.w;
        b[12] = a3.x; b[13] = a3.y; b[14] = a3.z; b[15] = a3.w;
    }
    const float* wp2 = &Ws2[k * KSTR + jb];
    float4 acc2 = b2[lane];
#pragma unroll
    for (int i = 0; i < 16; i++) {
        float4 wv = *(const float4*)&wp2[i * 16];
        acc2.x = fmaf(b[i], wv.x, acc2.x);
        acc2.y = fmaf(b[i], wv.y, acc2.y);
        acc2.z = fmaf(b[i], wv.z, acc2.z);
        acc2.w = fmaf(b[i], wv.w, acc2.w);
    }
    C[(size_t)n * 32 + lane] = acc2;
}

// ---------------- BN stats (standalone, for k_aggbd output) ----------------
__global__ __launch_bounds__(256) void k_stats(const float* __restrict__ X,
                                               float* __restrict__ st, int nrows) {
    int c = threadIdx.x & 127;
    int half = threadIdx.x >> 7;
    int rpb = (nrows + gridDim.x - 1) / gridDim.x;
    int r0 = blockIdx.x * rpb;
    int r1 = min(r0 + rpb, nrows);
    float s = 0.f, sq = 0.f;
    for (int r = r0 + half; r < r1; r += 2) {
        float v = X[(size_t)r * FF + c];
        s += v;
        sq += v * v;
    }
    atomicAdd(&st[c], s);
    atomicAdd(&st[FF + c], sq);
}

// ---------------- pooling with fused final BN ----------------
__global__ __launch_bounds__(128) void k_pool(const float* __restrict__ X,
                                              const int* __restrict__ batch,
                                              const float* __restrict__ st,
                                              const float* __restrict__ g,
                                              const float* __restrict__ be,
                                              float* __restrict__ out) {
    int c = threadIdx.x;
    const float inv_n = 1.0f / (float)NN;
    float mu = st[c] * inv_n;
    float var = st[FF + c] * inv_n - mu * mu;
    float a = g[c] * rsqrtf(var + BN_EPS);
    float b = be[c] - mu * a;
    int chunk = (NN + gridDim.x - 1) / gridDim.x;
    int r0 = blockIdx.x * chunk;
    int r1 = min(r0 + chunk, NN);
    if (r0 >= r1) return;
    float acc = 0.f;
    int cnt = 0;
    int cur = batch[r0];
    for (int r = r0; r < r1; r++) {
        int bb = batch[r];
        if (bb != cur) {
            atomicAdd(&out[(size_t)cur * FF + c], fmaf(a, acc, b * (float)cnt));
            acc = 0.f;
            cnt = 0;
            cur = bb;
        }
        acc += X[(size_t)r * FF + c];
        cnt++;
    }
    atomicAdd(&out[(size_t)cur * FF + c], fmaf(a, acc, b * (float)cnt));
}

extern "C" void kernel_launch(void* const* d_in, const int* in_sizes, int n_in,
                              void* d_out, int out_size, void* d_ws, size_t ws_size,
                              hipStream_t stream) {
    const float* x = (const float*)d_in[0];
    const int* ei = (const int*)d_in[1];
    const int* src = ei;
    const int* dst = ei + NE;
    const int* batch = (const int*)d_in[2];
    const float* gc_W1 = (const float*)d_in[4];
    const float* gc_b1 = (const float*)d_in[5];
    const float* gc_W2 = (const float*)d_in[6];
    const float* gc_b2 = (const float*)d_in[7];
    const float* gc_g = (const float*)d_in[8];
    const float* gc_be = (const float*)d_in[9];
    const float* h0_W1 = (const float*)d_in[10];
    const float* h0_b1 = (const float*)d_in[11];
    const float* h0_W2 = (const float*)d_in[12];
    const float* h0_b2 = (const float*)d_in[13];
    const float* h0_g = (const float*)d_in[14];
    const float* h0_be = (const float*)d_in[15];
    const float* h1_W1 = (const float*)d_in[16];
    const float* h1_b1 = (const float*)d_in[17];
    const float* h1_W2 = (const float*)d_in[18];
    const float* h1_b2 = (const float*)d_in[19];
    const float* h1_g = (const float*)d_in[20];
    const float* h1_be = (const float*)d_in[21];

    const size_t NF = (size_t)NN * FF;
    float* P0 = (float*)d_ws;
    float* P1 = P0 + NF;
    float* P2 = P1 + NF;
    float* stats = P2 + NF;
    int* deg = (int*)(stats + 5 * 256);
    int* cnt = deg + NN;
    int* offs = cnt + NN;
    int* bsum = offs + (NN + 4);
    int* boffs = bsum + 256;
    int* csr = boffs + 256;

    hipMemsetAsync(deg, 0, (size_t)2 * NN * sizeof(int), stream);
    hipMemsetAsync(stats, 0, 5 * 256 * sizeof(float), stream);
    hipMemsetAsync(d_out, 0, (size_t)GG * KF * DD * sizeof(float), stream);

    k_deg<<<(NE + 255) / 256, 256, 0, stream>>>(dst, deg);
    k_bsum<<<NB, 256, 0, stream>>>(deg, bsum);
    k_bscan<<<1, 256, 0, stream>>>(bsum, boffs);
    k_offs<<<NB, 256, 0, stream>>>(deg, boffs, offs);
    k_fill<<<(NE + 255) / 256, 256, 0, stream>>>(src, dst, offs, cnt, csr);

    const int fuse_grid = (NN + 63) / 64;  // 782
    const int agg_grid = NN / 8;           // 6250

    // ---- GC layers: fully fused agg+gemm-pair+stats ----
    k_fuse_pair<false, false><<<fuse_grid, 256, 0, stream>>>(
        (const float4*)x, offs, csr, nullptr, nullptr, nullptr,
        gc_W1, gc_b1, gc_W2, gc_b2, P0, stats);
    k_fuse_pair<true, true><<<fuse_grid, 256, 0, stream>>>(
        (const float4*)P0, offs, csr, stats, gc_g, gc_be,
        gc_W1 + FF * FF, gc_b1 + FF, gc_W2 + FF * FF, gc_b2 + FF, P1, stats + 256);
    k_fuse_pair<true, true><<<fuse_grid, 256, 0, stream>>>(
        (const float4*)P1, offs, csr, stats + 256, gc_g + FF, gc_be + FF,
        gc_W1 + 2 * FF * FF, gc_b1 + 2 * FF, gc_W2 + 2 * FF * FF, gc_b2 + 2 * FF, P0, stats + 512);

    // ---- head layer 0: fused agg(BN, no relu)+repack-gemm+blockdiag+stats ----
    k_fuse_h0<<<fuse_grid, 256, 0, stream>>>(
        (const float4*)P0, offs, csr, stats + 512, gc_g + 2 * FF, gc_be + 2 * FF,
        h0_W1, h0_b1, h0_W2, h0_b2, P1, stats + 768);

    // ---- head layer 1: fused agg(BN+relu) + double block-diag MLP ----
    k_aggbd<<<agg_grid, 256, 0, stream>>>(
        (const float4*)P1, offs, csr, stats + 768, h0_g, h0_be,
        h1_W1, (const float4*)h1_b1, h1_W2, (const float4*)h1_b2, (float4*)P2);
    k_stats<<<256, 256, 0, stream>>>(P2, stats + 1024, NN);

    // ---- pool with fused final BN ----
    k_pool<<<512, 128, 0, stream>>>(P2, batch, stats + 1024, h1_g, h1_be, (float*)d_out);
}

// Round 11
// 766.403 us; speedup vs baseline: 1.1930x; 1.1930x over previous
//
#include <hip/hip_runtime.h>

#define NN 50000
#define NE 800000
#define FF 128
#define KF 8
#define DD 16
#define GG 512
#define BN_EPS 1e-5f
#define NB 196   // ceil(NN/256)
#define KSTR 264 // padded k-block stride for block-diag weights

using s8v = __attribute__((ext_vector_type(8))) short;
using f4v = __attribute__((ext_vector_type(4))) float;

// ---------------- CSR build ----------------
__global__ void k_deg(const int* __restrict__ dst, int* __restrict__ deg) {
    int e = blockIdx.x * 256 + threadIdx.x;
    if (e < NE) atomicAdd(&deg[dst[e]], 1);
}

__global__ __launch_bounds__(256) void k_bsum(const int* __restrict__ deg, int* __restrict__ bsum) {
    int idx = blockIdx.x * 256 + threadIdx.x;
    int v = (idx < NN) ? deg[idx] : 0;
#pragma unroll
    for (int off = 32; off; off >>= 1) v += __shfl_down(v, off, 64);
    __shared__ int ws[4];
    if ((threadIdx.x & 63) == 0) ws[threadIdx.x >> 6] = v;
    __syncthreads();
    if (threadIdx.x == 0) bsum[blockIdx.x] = ws[0] + ws[1] + ws[2] + ws[3];
}

__global__ __launch_bounds__(256) void k_bscan(const int* __restrict__ bsum, int* __restrict__ boffs) {
    __shared__ int s[256];
    int tid = threadIdx.x;
    int v = (tid < NB) ? bsum[tid] : 0;
    s[tid] = v;
    __syncthreads();
    for (int off = 1; off < 256; off <<= 1) {
        int t = (tid >= off) ? s[tid - off] : 0;
        __syncthreads();
        s[tid] += t;
        __syncthreads();
    }
    if (tid < NB) boffs[tid] = s[tid] - v;  // exclusive
}

__global__ __launch_bounds__(256) void k_offs(const int* __restrict__ deg,
                                              const int* __restrict__ boffs,
                                              int* __restrict__ offs) {
    __shared__ int s[256];
    int tid = threadIdx.x;
    int idx = blockIdx.x * 256 + tid;
    int v = (idx < NN) ? deg[idx] : 0;
    s[tid] = v;
    __syncthreads();
    for (int off = 1; off < 256; off <<= 1) {
        int t = (tid >= off) ? s[tid - off] : 0;
        __syncthreads();
        s[tid] += t;
        __syncthreads();
    }
    int incl = s[tid];
    if (idx < NN) offs[idx] = boffs[blockIdx.x] + incl - v;
    if (idx == NN - 1) offs[NN] = boffs[blockIdx.x] + incl;
}

__global__ void k_fill(const int* __restrict__ src, const int* __restrict__ dst,
                       const int* __restrict__ offs, int* __restrict__ cnt,
                       int* __restrict__ csr) {
    int e = blockIdx.x * 256 + threadIdx.x;
    if (e < NE) {
        int d = dst[e];
        int p = atomicAdd(&cnt[d], 1);
        csr[offs[d] + p] = src[e];
    }
}

// ---------------- helpers ----------------
__device__ __forceinline__ void bn_coefs(const float* st, const float* g, const float* be,
                                         int lane, float4& a4, float4& b4) {
    const float inv_n = 1.0f / (float)NN;
    float av[4], bv[4];
#pragma unroll
    for (int t = 0; t < 4; t++) {
        int c = lane * 4 + t;
        float mu = st[c] * inv_n;
        float var = st[FF + c] * inv_n - mu * mu;
        float a = g[c] * rsqrtf(var + BN_EPS);
        av[t] = a;
        bv[t] = be[c] - mu * a;
    }
    a4 = make_float4(av[0], av[1], av[2], av[3]);
    b4 = make_float4(bv[0], bv[1], bv[2], bv[3]);
}

// split fp32 -> bf16 hi + bf16 lo (round-to-nearest-even both)
__device__ __forceinline__ void f2bf2(float v, unsigned short& hi, unsigned short& lo) {
    unsigned u = __float_as_uint(v);
    unsigned r = u + 0x7fffu + ((u >> 16) & 1u);
    hi = (unsigned short)(r >> 16);
    float hf = __uint_as_float(((unsigned)hi) << 16);
    float lf = v - hf;
    unsigned u2 = __float_as_uint(lf);
    unsigned r2 = u2 + 0x7fffu + ((u2 >> 16) & 1u);
    lo = (unsigned short)(r2 >> 16);
}

// ---------------- weight prep: fp32 [l][k][n] -> bf16 hi/lo transposed [n][k] -------
__global__ __launch_bounds__(256) void k_wprep(const float* __restrict__ W1,
                                               const float* __restrict__ W2,
                                               unsigned short* __restrict__ out) {
    int idx = blockIdx.x * 256 + threadIdx.x;  // over 3*2*16384
    if (idx >= 3 * 2 * 16384) return;
    int l = idx / (2 * 16384);
    int rem = idx % (2 * 16384);
    int mat = rem >> 14;
    int e = rem & 16383;
    int n = e >> 7, k = e & 127;
    const float* W = (mat == 0) ? (W1 + (size_t)l * 16384) : (W2 + (size_t)l * 16384);
    float v = W[k * 128 + n];
    unsigned short hi, lo;
    f2bf2(v, hi, lo);
    unsigned short* o = out + (size_t)((l * 2 + mat) * 2) * 16384;
    o[n * 128 + k] = hi;
    o[16384 + n * 128 + k] = lo;
}

// ---------------- aggregation with fused (optional) BN affine (+relu) on load ------
template <bool BN, bool RELU>
__global__ __launch_bounds__(256) void k_agg(const float4* __restrict__ X,
                                             const int* __restrict__ offs,
                                             const int* __restrict__ csr,
                                             const float* __restrict__ st,
                                             const float* __restrict__ g,
                                             const float* __restrict__ be,
                                             float4* __restrict__ Z) {
    int grp = threadIdx.x >> 5;
    int lane = threadIdx.x & 31;
    int n = blockIdx.x * 8 + grp;

    float4 a4 = make_float4(1.f, 1.f, 1.f, 1.f);
    float4 b4 = make_float4(0.f, 0.f, 0.f, 0.f);
    if (BN) bn_coefs(st, g, be, lane, a4, b4);

    auto apply = [&](float4 v) -> float4 {
        if (BN) {
            v.x = fmaf(v.x, a4.x, b4.x);
            v.y = fmaf(v.y, a4.y, b4.y);
            v.z = fmaf(v.z, a4.z, b4.z);
            v.w = fmaf(v.w, a4.w, b4.w);
        }
        if (RELU) {
            v.x = fmaxf(v.x, 0.f);
            v.y = fmaxf(v.y, 0.f);
            v.z = fmaxf(v.z, 0.f);
            v.w = fmaxf(v.w, 0.f);
        }
        return v;
    };
    auto add4 = [](float4& a, float4 b) {
        a.x += b.x; a.y += b.y; a.z += b.z; a.w += b.w;
    };

    float4 acc = apply(X[(size_t)n * 32 + lane]);
    int e0 = offs[n], e1 = offs[n + 1];
    int e = e0;
    for (; e + 8 <= e1; e += 8) {
        int s0 = csr[e], s1 = csr[e + 1], s2 = csr[e + 2], s3 = csr[e + 3];
        int s4 = csr[e + 4], s5 = csr[e + 5], s6 = csr[e + 6], s7 = csr[e + 7];
        float4 v0 = X[(size_t)s0 * 32 + lane];
        float4 v1 = X[(size_t)s1 * 32 + lane];
        float4 v2 = X[(size_t)s2 * 32 + lane];
        float4 v3 = X[(size_t)s3 * 32 + lane];
        float4 v4 = X[(size_t)s4 * 32 + lane];
        float4 v5 = X[(size_t)s5 * 32 + lane];
        float4 v6 = X[(size_t)s6 * 32 + lane];
        float4 v7 = X[(size_t)s7 * 32 + lane];
        v0 = apply(v0); v1 = apply(v1); v2 = apply(v2); v3 = apply(v3);
        v4 = apply(v4); v5 = apply(v5); v6 = apply(v6); v7 = apply(v7);
        add4(v0, v1); add4(v2, v3); add4(v4, v5); add4(v6, v7);
        add4(v0, v2); add4(v4, v6); add4(v0, v4); add4(acc, v0);
    }
    for (; e + 4 <= e1; e += 4) {
        int s0 = csr[e], s1 = csr[e + 1], s2 = csr[e + 2], s3 = csr[e + 3];
        float4 v0 = apply(X[(size_t)s0 * 32 + lane]);
        float4 v1 = apply(X[(size_t)s1 * 32 + lane]);
        float4 v2 = apply(X[(size_t)s2 * 32 + lane]);
        float4 v3 = apply(X[(size_t)s3 * 32 + lane]);
        add4(v0, v1); add4(v2, v3); add4(v0, v2); add4(acc, v0);
    }
    for (; e < e1; e++) {
        float4 v = apply(X[(size_t)csr[e] * 32 + lane]);
        add4(acc, v);
    }
    Z[(size_t)n * 32 + lane] = acc;
}

// ============ MFMA bf16x3 GEMM pair: C = relu(A@W1+b1)@W2 + b2, + stats ============
// A split to bf16 hi/lo in LDS (row-major, stride 136 = 16B-aligned). W pre-split &
// transposed (WT[part][n][k]) by k_wprep; staged per 32-k chunk. 3 mfma terms:
// hi*hi + lo*hi + hi*lo (fp32 accumulate) ~= fp32 GEMM.
// Layouts (guide-verified): A[m=lane&15][k=quad*8+j]; B[k=quad*8+j][n=lane&15];
// C/D col=lane&15, row=quad*4+reg.
__global__ __launch_bounds__(256) void gemm_mfma(const float4* __restrict__ A,
                                                 const unsigned short* __restrict__ W1T,
                                                 const unsigned short* __restrict__ W2T,
                                                 const float* __restrict__ b1,
                                                 const float* __restrict__ b2,
                                                 float* __restrict__ C,
                                                 float* __restrict__ stout) {
    __shared__ __align__(16) unsigned short Abf[2 * 64 * 136];  // 34816 B
    __shared__ __align__(16) unsigned short Wch[2 * 128 * 40];  // 20480 B
    int tid = threadIdx.x;
    int row0 = blockIdx.x * 64;
    int w = tid >> 6, lane = tid & 63, quad = lane >> 4, lid = lane & 15;

    // stage A -> bf16 hi/lo (row-major)
#pragma unroll
    for (int i = 0; i < 8; i++) {
        int l = tid + i * 256;       // 0..2047 over 64 rows x 32 float4
        int r = l >> 5, q4 = l & 31;
        int gr = row0 + r;
        if (gr >= NN) gr = NN - 1;   // clamp (excluded from store/stats)
        float4 v = A[(size_t)gr * 32 + q4];
        unsigned short h0, l0, h1, l1, h2, l2, h3, l3;
        f2bf2(v.x, h0, l0); f2bf2(v.y, h1, l1);
        f2bf2(v.z, h2, l2); f2bf2(v.w, h3, l3);
        *(ushort4*)&Abf[r * 136 + q4 * 4] = make_ushort4(h0, h1, h2, h3);
        *(ushort4*)&Abf[8704 + r * 136 + q4 * 4] = make_ushort4(l0, l1, l2, l3);
    }
    __syncthreads();

    f4v acc[8];
#pragma unroll
    for (int i = 0; i < 8; i++) acc[i] = 0;

    // ---- phase 1: z = relu(A@W1 + b1) ----
    for (int kc = 0; kc < 4; kc++) {
#pragma unroll
        for (int i = 0; i < 8; i++) {  // stage W chunk: 2 parts x 128 n x 8 k-quads
            int l = tid + i * 256;
            int part = l >> 10, rem = l & 1023;
            int n = rem >> 3, kq = rem & 7;
            ushort4 v = *(const ushort4*)&W1T[(size_t)part * 16384 + n * 128 + kc * 32 + kq * 4];
            *(ushort4*)&Wch[part * 5120 + n * 40 + kq * 4] = v;
        }
        __syncthreads();
        s8v ah = *(const s8v*)&Abf[(w * 16 + lid) * 136 + kc * 32 + quad * 8];
        s8v al = *(const s8v*)&Abf[8704 + (w * 16 + lid) * 136 + kc * 32 + quad * 8];
#pragma unroll
        for (int n0 = 0; n0 < 8; n0++) {
            s8v bh = *(const s8v*)&Wch[(n0 * 16 + lid) * 40 + quad * 8];
            s8v bl = *(const s8v*)&Wch[5120 + (n0 * 16 + lid) * 40 + quad * 8];
            acc[n0] = __builtin_amdgcn_mfma_f32_16x16x32_bf16(ah, bh, acc[n0], 0, 0, 0);
            acc[n0] = __builtin_amdgcn_mfma_f32_16x16x32_bf16(al, bh, acc[n0], 0, 0, 0);
            acc[n0] = __builtin_amdgcn_mfma_f32_16x16x32_bf16(ah, bl, acc[n0], 0, 0, 0);
        }
        __syncthreads();
    }

    // z = relu(acc+b1) -> Abf bf16 hi/lo. Rows w*16+quad*4+rr are THIS wave's rows;
    // phase-2 reads them in the same wave after the kc=0 barrier -> no extra barrier.
#pragma unroll
    for (int n0 = 0; n0 < 8; n0++) {
        int c = n0 * 16 + lid;
        float bb = b1[c];
#pragma unroll
        for (int rr = 0; rr < 4; rr++) {
            int lr = w * 16 + quad * 4 + rr;
            float z = fmaxf(acc[n0][rr] + bb, 0.f);
            unsigned short h, lo2;
            f2bf2(z, h, lo2);
            Abf[lr * 136 + c] = h;
            Abf[8704 + lr * 136 + c] = lo2;
        }
        acc[n0] = 0;
    }

    // ---- phase 2: C = z@W2 + b2 ----
    for (int kc = 0; kc < 4; kc++) {
#pragma unroll
        for (int i = 0; i < 8; i++) {
            int l = tid + i * 256;
            int part = l >> 10, rem = l & 1023;
            int n = rem >> 3, kq = rem & 7;
            ushort4 v = *(const ushort4*)&W2T[(size_t)part * 16384 + n * 128 + kc * 32 + kq * 4];
            *(ushort4*)&Wch[part * 5120 + n * 40 + kq * 4] = v;
        }
        __syncthreads();
        s8v ah = *(const s8v*)&Abf[(w * 16 + lid) * 136 + kc * 32 + quad * 8];
        s8v al = *(const s8v*)&Abf[8704 + (w * 16 + lid) * 136 + kc * 32 + quad * 8];
#pragma unroll
        for (int n0 = 0; n0 < 8; n0++) {
            s8v bh = *(const s8v*)&Wch[(n0 * 16 + lid) * 40 + quad * 8];
            s8v bl = *(const s8v*)&Wch[5120 + (n0 * 16 + lid) * 40 + quad * 8];
            acc[n0] = __builtin_amdgcn_mfma_f32_16x16x32_bf16(ah, bh, acc[n0], 0, 0, 0);
            acc[n0] = __builtin_amdgcn_mfma_f32_16x16x32_bf16(al, bh, acc[n0], 0, 0, 0);
            acc[n0] = __builtin_amdgcn_mfma_f32_16x16x32_bf16(ah, bl, acc[n0], 0, 0, 0);
        }
        __syncthreads();
    }

    // ---- epilogue: bias, store, stats (shuffle-reduce over quads) ----
    float* Sred = (float*)Wch;  // 1024 floats; Wch free after last barrier
#pragma unroll
    for (int n0 = 0; n0 < 8; n0++) {
        int c = n0 * 16 + lid;
        float bb = b2[c];
        float s = 0.f, q = 0.f;
#pragma unroll
        for (int rr = 0; rr < 4; rr++) {
            int grow = row0 + w * 16 + quad * 4 + rr;
            if (grow < NN) {
                float v = acc[n0][rr] + bb;
                C[(size_t)grow * 128 + c] = v;
                s += v;
                q += v * v;
            }
        }
        s += __shfl_xor(s, 16); s += __shfl_xor(s, 32);
        q += __shfl_xor(q, 16); q += __shfl_xor(q, 32);
        if (quad == 0) {
            Sred[w * 128 + c] = s;
            Sred[512 + w * 128 + c] = q;
        }
    }
    __syncthreads();
    if (tid < 128) {
        float s = Sred[tid] + Sred[128 + tid] + Sred[256 + tid] + Sred[384 + tid];
        float q = Sred[512 + tid] + Sred[640 + tid] + Sred[768 + tid] + Sred[896 + tid];
        atomicAdd(&stout[tid], s);
        atomicAdd(&stout[FF + tid], q);
    }
}

// ============ fused h0: C = relu(A@W1cat+b1) @ blockdiag(W2) + b2, + stats ============
// (R7-proven VALU version: 40KB LDS, conflict-free column remap, no prefetch)
__global__ __launch_bounds__(256, 4) void gemm_h0(const float* __restrict__ A,
                                                  const float* __restrict__ W1,  // [K,F,d]
                                                  const float* __restrict__ b1,  // [K*d]
                                                  const float* __restrict__ W2,  // [K,d,d]
                                                  const float* __restrict__ b2,  // [K*d]
                                                  float* __restrict__ C, int nrows,
                                                  float* __restrict__ st) {
    __shared__ float Zs[64 * 128];
    __shared__ float Ws[KF * KSTR];  // phase-1 uses first 2048 as [16][128]
    float* Af = Zs;
    int row0 = blockIdx.x * 64;
    int tid = threadIdx.x;
    int m = tid & 15;
    int tr = (tid >> 4) << 2;
    int c0 = m << 2, c1 = 64 + (m << 2);
    int swz = ((tid >> 4) & 3) << 2;
    float acc[4][8];
#pragma unroll
    for (int i = 0; i < 4; i++)
#pragma unroll
        for (int j = 0; j < 8; j++) acc[i][j] = 0.f;

    for (int f0 = 0; f0 < 128; f0 += 16) {
        {
            int r = tid >> 2, q = tid & 3;
            int gr = row0 + r;
            if (gr >= nrows) gr = nrows - 1;
            float4 v = ((const float4*)A)[(size_t)gr * 32 + (f0 >> 2) + q];
            Af[(q * 4 + 0) * 68 + r] = v.x;
            Af[(q * 4 + 1) * 68 + r] = v.y;
            Af[(q * 4 + 2) * 68 + r] = v.z;
            Af[(q * 4 + 3) * 68 + r] = v.w;
        }
#pragma unroll
        for (int i = 0; i < 2; i++) {
            int l = tid + i * 256;
            int f = l >> 5, q = l & 31;
            float4 wv = *(const float4*)&W1[(q >> 2) * (FF * DD) + (size_t)(f0 + f) * DD + (q & 3) * 4];
            ((float4*)Ws)[f * 32 + q] = wv;
        }
        __syncthreads();
#pragma unroll 8
        for (int f = 0; f < 16; f++) {
            float4 a04 = *(const float4*)&Af[f * 68 + tr];
            float a[4] = {a04.x, a04.y, a04.z, a04.w};
            float4 w0 = *(const float4*)&Ws[f * 128 + c0];
            float4 w1 = *(const float4*)&Ws[f * 128 + c1];
            float wv[8] = {w0.x, w0.y, w0.z, w0.w, w1.x, w1.y, w1.z, w1.w};
#pragma unroll
            for (int i = 0; i < 4; i++)
#pragma unroll
                for (int j = 0; j < 8; j++) acc[i][j] = fmaf(a[i], wv[j], acc[i][j]);
        }
        __syncthreads();
    }
    {
        float4 bb0 = *(const float4*)&b1[c0];
        float4 bb1 = *(const float4*)&b1[c1];
#pragma unroll
        for (int i = 0; i < 4; i++) {
            int r = tr + i;
            float4 z0 = make_float4(fmaxf(acc[i][0] + bb0.x, 0.f), fmaxf(acc[i][1] + bb0.y, 0.f),
                                    fmaxf(acc[i][2] + bb0.z, 0.f), fmaxf(acc[i][3] + bb0.w, 0.f));
            float4 z1 = make_float4(fmaxf(acc[i][4] + bb1.x, 0.f), fmaxf(acc[i][5] + bb1.y, 0.f),
                                    fmaxf(acc[i][6] + bb1.z, 0.f), fmaxf(acc[i][7] + bb1.w, 0.f));
            *(float4*)&Zs[r * 128 + (c0 ^ swz)] = z0;
            *(float4*)&Zs[r * 128 + (c1 ^ swz)] = z1;
        }
    }
    for (int l = tid; l < KF * 256; l += 256) {
        int k = l >> 8, r2 = l & 255;
        Ws[k * KSTR + r2] = W2[l];
    }
    __syncthreads();

    int k0 = m >> 2, k1 = 4 + (m >> 2);
    int j0 = (m & 3) << 2;
    float y[4][8];
#pragma unroll
    for (int i = 0; i < 4; i++)
#pragma unroll
        for (int j = 0; j < 8; j++) y[i][j] = 0.f;
#pragma unroll
    for (int ii = 0; ii < 16; ii++) {
        int fc0 = (k0 * 16 + ii) ^ swz;
        int fc1 = (k1 * 16 + ii) ^ swz;
        float4 w0 = *(const float4*)&Ws[k0 * KSTR + ii * 16 + j0];
        float4 w1 = *(const float4*)&Ws[k1 * KSTR + ii * 16 + j0];
#pragma unroll
        for (int i = 0; i < 4; i++) {
            float a0 = Zs[(tr + i) * 128 + fc0];
            float a1 = Zs[(tr + i) * 128 + fc1];
            y[i][0] = fmaf(a0, w0.x, y[i][0]);
            y[i][1] = fmaf(a0, w0.y, y[i][1]);
            y[i][2] = fmaf(a0, w0.z, y[i][2]);
            y[i][3] = fmaf(a0, w0.w, y[i][3]);
            y[i][4] = fmaf(a1, w1.x, y[i][4]);
            y[i][5] = fmaf(a1, w1.y, y[i][5]);
            y[i][6] = fmaf(a1, w1.z, y[i][6]);
            y[i][7] = fmaf(a1, w1.w, y[i][7]);
        }
    }

    float cs[8], cq[8];
#pragma unroll
    for (int j = 0; j < 8; j++) { cs[j] = 0.f; cq[j] = 0.f; }
    {
        float4 bb0 = *(const float4*)&b2[c0];
        float4 bb1 = *(const float4*)&b2[c1];
        float bbias[8] = {bb0.x, bb0.y, bb0.z, bb0.w, bb1.x, bb1.y, bb1.z, bb1.w};
#pragma unroll
        for (int i = 0; i < 4; i++) {
            int r = row0 + tr + i;
            if (r < nrows) {
                float v[8];
#pragma unroll
                for (int j = 0; j < 8; j++) {
                    v[j] = y[i][j] + bbias[j];
                    cs[j] += v[j];
                    cq[j] += v[j] * v[j];
                }
                *(float4*)&C[(size_t)r * 128 + c0] = make_float4(v[0], v[1], v[2], v[3]);
                *(float4*)&C[(size_t)r * 128 + c1] = make_float4(v[4], v[5], v[6], v[7]);
            }
        }
    }
    {
        float* S1 = Zs;
        float* S2 = Zs + 4096;
        int grp = tid >> 4;
        __syncthreads();
#pragma unroll
        for (int j = 0; j < 8; j++) {
            int c = (j < 4) ? c0 + j : c1 + (j - 4);
            S1[grp * 128 + c] = cs[j];
            S2[grp * 128 + c] = cq[j];
        }
        __syncthreads();
        if (tid < 128) {
            float s = 0.f, q = 0.f;
#pragma unroll
            for (int gi = 0; gi < 16; gi++) {
                s += S1[gi * 128 + tid];
                q += S2[gi * 128 + tid];
            }
            atomicAdd(&st[tid], s);
            atomicAdd(&st[FF + tid], q);
        }
    }
}

// ---------------- fused h1: agg(BN+relu on load) + double block-diag MLP -----------
__global__ __launch_bounds__(256) void k_aggbd(const float4* __restrict__ X,
                                               const int* __restrict__ offs,
                                               const int* __restrict__ csr,
                                               const float* __restrict__ st,
                                               const float* __restrict__ g,
                                               const float* __restrict__ be,
                                               const float* __restrict__ W1,
                                               const float4* __restrict__ b1,
                                               const float* __restrict__ W2,
                                               const float4* __restrict__ b2,
                                               float4* __restrict__ C) {
    __shared__ float As[8][128];
    __shared__ float Ts[8][128];
    __shared__ float Ws1[KF * KSTR];
    __shared__ float Ws2[KF * KSTR];
    int grp = threadIdx.x >> 5, lane = threadIdx.x & 31;
    int n = blockIdx.x * 8 + grp;

    for (int l = threadIdx.x; l < KF * 256; l += 256) {
        int k = l >> 8, r = l & 255;
        Ws1[k * KSTR + r] = W1[l];
        Ws2[k * KSTR + r] = W2[l];
    }

    float4 a4, b4;
    bn_coefs(st, g, be, lane, a4, b4);
    auto apply = [&](float4 v) -> float4 {
        v.x = fmaxf(fmaf(v.x, a4.x, b4.x), 0.f);
        v.y = fmaxf(fmaf(v.y, a4.y, b4.y), 0.f);
        v.z = fmaxf(fmaf(v.z, a4.z, b4.z), 0.f);
        v.w = fmaxf(fmaf(v.w, a4.w, b4.w), 0.f);
        return v;
    };
    auto add4 = [](float4& a, float4 b) {
        a.x += b.x; a.y += b.y; a.z += b.z; a.w += b.w;
    };

    float4 acc = apply(X[(size_t)n * 32 + lane]);
    int e0 = offs[n], e1 = offs[n + 1];
    int e = e0;
    for (; e + 8 <= e1; e += 8) {
        int s0 = csr[e], s1 = csr[e + 1], s2 = csr[e + 2], s3 = csr[e + 3];
        int s4 = csr[e + 4], s5 = csr[e + 5], s6 = csr[e + 6], s7 = csr[e + 7];
        float4 v0 = X[(size_t)s0 * 32 + lane];
        float4 v1 = X[(size_t)s1 * 32 + lane];
        float4 v2 = X[(size_t)s2 * 32 + lane];
        float4 v3 = X[(size_t)s3 * 32 + lane];
        float4 v4 = X[(size_t)s4 * 32 + lane];
        float4 v5 = X[(size_t)s5 * 32 + lane];
        float4 v6 = X[(size_t)s6 * 32 + lane];
        float4 v7 = X[(size_t)s7 * 32 + lane];
        v0 = apply(v0); v1 = apply(v1); v2 = apply(v2); v3 = apply(v3);
        v4 = apply(v4); v5 = apply(v5); v6 = apply(v6); v7 = apply(v7);
        add4(v0, v1); add4(v2, v3); add4(v4, v5); add4(v6, v7);
        add4(v0, v2); add4(v4, v6); add4(v0, v4); add4(acc, v0);
    }
    for (; e + 4 <= e1; e += 4) {
        int s0 = csr[e], s1 = csr[e + 1], s2 = csr[e + 2], s3 = csr[e + 3];
        float4 v0 = apply(X[(size_t)s0 * 32 + lane]);
        float4 v1 = apply(X[(size_t)s1 * 32 + lane]);
        float4 v2 = apply(X[(size_t)s2 * 32 + lane]);
        float4 v3 = apply(X[(size_t)s3 * 32 + lane]);
        add4(v0, v1); add4(v2, v3); add4(v0, v2); add4(acc, v0);
    }
    for (; e < e1; e++) {
        float4 v = apply(X[(size_t)csr[e] * 32 + lane]);
        add4(acc, v);
    }
    ((float4*)&As[grp][0])[lane] = acc;
    __syncthreads();

    int k = lane >> 2, jb = (lane & 3) * 4;
    float a[16];
    {
        const float4* As4 = (const float4*)&As[grp][k * 16];
        float4 a0 = As4[0], a1 = As4[1], a2 = As4[2], a3 = As4[3];
        a[0] = a0.x; a[1] = a0.y; a[2] = a0.z; a[3] = a0.w;
        a[4] = a1.x; a[5] = a1.y; a[6] = a1.z; a[7] = a1.w;
        a[8] = a2.x; a[9] = a2.y; a[10] = a2.z; a[11] = a2.w;
        a[12] = a3.x; a[13] = a3.y; a[14] = a3.z; a[15] = a3.w;
    }
    const float* wp1 = &Ws1[k * KSTR + jb];
    float4 t = b1[lane];
#pragma unroll
    for (int i = 0; i < 16; i++) {
        float4 wv = *(const float4*)&wp1[i * 16];
        t.x = fmaf(a[i], wv.x, t.x);
        t.y = fmaf(a[i], wv.y, t.y);
        t.z = fmaf(a[i], wv.z, t.z);
        t.w = fmaf(a[i], wv.w, t.w);
    }
    t.x = fmaxf(t.x, 0.f); t.y = fmaxf(t.y, 0.f);
    t.z = fmaxf(t.z, 0.f); t.w = fmaxf(t.w, 0.f);
    ((float4*)&Ts[grp][0])[lane] = t;
    __syncthreads();

    float b[16];
    {
        const float4* Ts4 = (const float4*)&Ts[grp][k * 16];
        float4 a0 = Ts4[0], a1 = Ts4[1], a2 = Ts4[2], a3 = Ts4[3];
        b[0] = a0.x; b[1] = a0.y; b[2] = a0.z; b[3] = a0.w;
        b[4] = a1.x; b[5] = a1.y; b[6] = a1.z; b[7] = a1.w;
        b[8] = a2.x; b[9] = a2.y; b[10] = a2.z; b[11] = a2.w;
        b[12] = a3.x; b[13] = a3.y; b[14] = a3.z; b[15] = a3.w;
    }
    const float* wp2 = &Ws2[k * KSTR + jb];
    float4 acc2 = b2[lane];
#pragma unroll
    for (int i = 0; i < 16; i++) {
        float4 wv = *(const float4*)&wp2[i * 16];
        acc2.x = fmaf(b[i], wv.x, acc2.x);
        acc2.y = fmaf(b[i], wv.y, acc2.y);
        acc2.z = fmaf(b[i], wv.z, acc2.z);
        acc2.w = fmaf(b[i], wv.w, acc2.w);
    }
    C[(size_t)n * 32 + lane] = acc2;
}

// ---------------- BN stats (standalone, for k_aggbd output) ----------------
__global__ __launch_bounds__(256) void k_stats(const float* __restrict__ X,
                                               float* __restrict__ st, int nrows) {
    int c = threadIdx.x & 127;
    int half = threadIdx.x >> 7;
    int rpb = (nrows + gridDim.x - 1) / gridDim.x;
    int r0 = blockIdx.x * rpb;
    int r1 = min(r0 + rpb, nrows);
    float s = 0.f, sq = 0.f;
    for (int r = r0 + half; r < r1; r += 2) {
        float v = X[(size_t)r * FF + c];
        s += v;
        sq += v * v;
    }
    atomicAdd(&st[c], s);
    atomicAdd(&st[FF + c], sq);
}

// ---------------- pooling with fused final BN ----------------
__global__ __launch_bounds__(128) void k_pool(const float* __restrict__ X,
                                              const int* __restrict__ batch,
                                              const float* __restrict__ st,
                                              const float* __restrict__ g,
                                              const float* __restrict__ be,
                                              float* __restrict__ out) {
    int c = threadIdx.x;
    const float inv_n = 1.0f / (float)NN;
    float mu = st[c] * inv_n;
    float var = st[FF + c] * inv_n - mu * mu;
    float a = g[c] * rsqrtf(var + BN_EPS);
    float b = be[c] - mu * a;
    int chunk = (NN + gridDim.x - 1) / gridDim.x;
    int r0 = blockIdx.x * chunk;
    int r1 = min(r0 + chunk, NN);
    if (r0 >= r1) return;
    float acc = 0.f;
    int cnt = 0;
    int cur = batch[r0];
    for (int r = r0; r < r1; r++) {
        int bb = batch[r];
        if (bb != cur) {
            atomicAdd(&out[(size_t)cur * FF + c], fmaf(a, acc, b * (float)cnt));
            acc = 0.f;
            cnt = 0;
            cur = bb;
        }
        acc += X[(size_t)r * FF + c];
        cnt++;
    }
    atomicAdd(&out[(size_t)cur * FF + c], fmaf(a, acc, b * (float)cnt));
}

extern "C" void kernel_launch(void* const* d_in, const int* in_sizes, int n_in,
                              void* d_out, int out_size, void* d_ws, size_t ws_size,
                              hipStream_t stream) {
    const float* x = (const float*)d_in[0];
    const int* ei = (const int*)d_in[1];
    const int* src = ei;
    const int* dst = ei + NE;
    const int* batch = (const int*)d_in[2];
    const float* gc_W1 = (const float*)d_in[4];
    const float* gc_b1 = (const float*)d_in[5];
    const float* gc_W2 = (const float*)d_in[6];
    const float* gc_b2 = (const float*)d_in[7];
    const float* gc_g = (const float*)d_in[8];
    const float* gc_be = (const float*)d_in[9];
    const float* h0_W1 = (const float*)d_in[10];
    const float* h0_b1 = (const float*)d_in[11];
    const float* h0_W2 = (const float*)d_in[12];
    const float* h0_b2 = (const float*)d_in[13];
    const float* h0_g = (const float*)d_in[14];
    const float* h0_be = (const float*)d_in[15];
    const float* h1_W1 = (const float*)d_in[16];
    const float* h1_b1 = (const float*)d_in[17];
    const float* h1_W2 = (const float*)d_in[18];
    const float* h1_b2 = (const float*)d_in[19];
    const float* h1_g = (const float*)d_in[20];
    const float* h1_be = (const float*)d_in[21];

    const size_t NF = (size_t)NN * FF;
    float* P0 = (float*)d_ws;
    float* P1 = P0 + NF;
    float* P2 = P1 + NF;
    float* stats = P2 + NF;
    int* deg = (int*)(stats + 5 * 256);
    int* cnt = deg + NN;
    int* offs = cnt + NN;
    int* bsum = offs + (NN + 4);
    int* boffs = bsum + 256;
    int* csr = boffs + 256;
    unsigned short* wbf = (unsigned short*)(csr + NE);  // 3 layers x 2 mats x 2 parts x 16384

    hipMemsetAsync(deg, 0, (size_t)2 * NN * sizeof(int), stream);
    hipMemsetAsync(stats, 0, 5 * 256 * sizeof(float), stream);
    hipMemsetAsync(d_out, 0, (size_t)GG * KF * DD * sizeof(float), stream);

    k_deg<<<(NE + 255) / 256, 256, 0, stream>>>(dst, deg);
    k_bsum<<<NB, 256, 0, stream>>>(deg, bsum);
    k_bscan<<<1, 256, 0, stream>>>(bsum, boffs);
    k_offs<<<NB, 256, 0, stream>>>(deg, boffs, offs);
    k_fill<<<(NE + 255) / 256, 256, 0, stream>>>(src, dst, offs, cnt, csr);
    k_wprep<<<(3 * 2 * 16384 + 255) / 256, 256, 0, stream>>>(gc_W1, gc_W2, wbf);

    const int agg_grid = NN / 8;            // 6250
    const int gemm_grid = (NN + 63) / 64;   // 782

    // ---- GC layers: agg + MFMA bf16x3 gemm pair (stats fused) ----
    k_agg<false, false><<<agg_grid, 256, 0, stream>>>(
        (const float4*)x, offs, csr, nullptr, nullptr, nullptr, (float4*)P0);
    gemm_mfma<<<gemm_grid, 256, 0, stream>>>(
        (const float4*)P0, wbf + 0 * 32768, wbf + 1 * 32768, gc_b1, gc_b2, P2, stats);

    k_agg<true, true><<<agg_grid, 256, 0, stream>>>(
        (const float4*)P2, offs, csr, stats, gc_g, gc_be, (float4*)P0);
    gemm_mfma<<<gemm_grid, 256, 0, stream>>>(
        (const float4*)P0, wbf + 2 * 32768, wbf + 3 * 32768, gc_b1 + FF, gc_b2 + FF, P2, stats + 256);

    k_agg<true, true><<<agg_grid, 256, 0, stream>>>(
        (const float4*)P2, offs, csr, stats + 256, gc_g + FF, gc_be + FF, (float4*)P0);
    gemm_mfma<<<gemm_grid, 256, 0, stream>>>(
        (const float4*)P0, wbf + 4 * 32768, wbf + 5 * 32768, gc_b1 + 2 * FF, gc_b2 + 2 * FF, P2, stats + 512);

    // ---- head layer 0: agg (GC2 BN, no relu) + fused repack-gemm/bd/stats ----
    k_agg<true, false><<<agg_grid, 256, 0, stream>>>(
        (const float4*)P2, offs, csr, stats + 512, gc_g + 2 * FF, gc_be + 2 * FF, (float4*)P0);
    gemm_h0<<<gemm_grid, 256, 0, stream>>>(P0, h0_W1, h0_b1, h0_W2, h0_b2, P1, NN, stats + 768);

    // ---- head layer 1: fused agg(BN+relu) + double block-diag MLP ----
    k_aggbd<<<agg_grid, 256, 0, stream>>>(
        (const float4*)P1, offs, csr, stats + 768, h0_g, h0_be,
        h1_W1, (const float4*)h1_b1, h1_W2, (const float4*)h1_b2, (float4*)P2);
    k_stats<<<256, 256, 0, stream>>>(P2, stats + 1024, NN);

    // ---- pool with fused final BN ----
    k_pool<<<512, 128, 0, stream>>>(P2, batch, stats + 1024, h1_g, h1_be, (float*)d_out);
}